// Round 2
// baseline (2745.537 us; speedup 1.0000x reference)
//
#include <hip/hip_runtime.h>
#include <hip/hip_bf16.h>
#include <math.h>

#define NB 8192
#define ND 512
#define NCLS 100

constexpr float INV_T = 1.0f / 0.07f;   // 14.2857143
constexpr float MAXL  = 1.0f / 0.07f;   // fixed LSE max: |dot|<=1 since rows normalized

#define TI 16      // rows per block (staged in LDS)
#define TJ 4       // columns per thread per tile
#define THREADS 256

// ---------------- setup: class histogram + member lists + zero accum --------
__global__ __launch_bounds__(256) void setup_kernel(const int* __restrict__ labels,
                                                    int* cls_cnt, int* cls_off,
                                                    int* cls_cur, int* members,
                                                    double* accum) {
    __shared__ int s_cnt[NCLS];
    const int t = threadIdx.x;
    if (t < NCLS) s_cnt[t] = 0;
    if (t == 0) *accum = 0.0;
    __syncthreads();
    for (int j = t; j < NB; j += blockDim.x) atomicAdd(&s_cnt[labels[j]], 1);
    __syncthreads();
    if (t < NCLS) cls_cnt[t] = s_cnt[t];
    __syncthreads();
    if (t == 0) {
        int off = 0;
        for (int c = 0; c < NCLS; ++c) { cls_off[c] = off; cls_cur[c] = off; off += s_cnt[c]; }
    }
    __syncthreads();
    for (int j = t; j < NB; j += blockDim.x) {
        const int c = labels[j];
        const int pos = atomicAdd(&cls_cur[c], 1);
        members[pos] = j;
    }
}

// ---------------- pass 1: base_row[i] = C + log( sum_{label_j != label_i} exp(S_ij - C) )
__global__ __launch_bounds__(THREADS) void pass1_kernel(const float* __restrict__ E,
                                                        const int* __restrict__ labels,
                                                        float* __restrict__ base_row) {
    __shared__ float e_tile[TI][ND];
    __shared__ int   s_rowlab[TI];
    __shared__ float s_part[4][TI];

    const int t  = threadIdx.x;
    const int i0 = blockIdx.x * TI;

    {   // coalesced stage of TI rows into LDS (16*512 floats = 2048 float4)
        const float4* src = (const float4*)(E + (size_t)i0 * ND);
        float4* dst = (float4*)(&e_tile[0][0]);
        #pragma unroll
        for (int k = 0; k < (TI * ND / 4) / THREADS; ++k)
            dst[t + k * THREADS] = src[t + k * THREADS];
    }
    if (t < TI) s_rowlab[t] = labels[i0 + t];
    __syncthreads();

    int rowlab[TI];
    #pragma unroll
    for (int r = 0; r < TI; ++r) rowlab[r] = s_rowlab[r];

    float acc[TI];
    #pragma unroll
    for (int r = 0; r < TI; ++r) acc[r] = 0.f;

    for (int jt = 0; jt < NB; jt += THREADS * TJ) {
        float dot[TI][TJ];
        #pragma unroll
        for (int r = 0; r < TI; ++r)
            #pragma unroll
            for (int q = 0; q < TJ; ++q) dot[r][q] = 0.f;

        const float* jp[TJ];
        #pragma unroll
        for (int q = 0; q < TJ; ++q)
            jp[q] = E + (size_t)(jt + t + q * THREADS) * ND;

        for (int d = 0; d < ND; d += 4) {
            float4 ev[TJ];
            #pragma unroll
            for (int q = 0; q < TJ; ++q) ev[q] = *(const float4*)(jp[q] + d);
            #pragma unroll
            for (int r = 0; r < TI; ++r) {
                const float4 er = *(const float4*)(&e_tile[r][d]);
                #pragma unroll
                for (int q = 0; q < TJ; ++q) {
                    dot[r][q] = fmaf(er.x, ev[q].x, dot[r][q]);
                    dot[r][q] = fmaf(er.y, ev[q].y, dot[r][q]);
                    dot[r][q] = fmaf(er.z, ev[q].z, dot[r][q]);
                    dot[r][q] = fmaf(er.w, ev[q].w, dot[r][q]);
                }
            }
        }
        #pragma unroll
        for (int q = 0; q < TJ; ++q) {
            const int lj = labels[jt + t + q * THREADS];
            #pragma unroll
            for (int r = 0; r < TI; ++r) {
                const float e = __expf(dot[r][q] * INV_T - MAXL);
                acc[r] += (lj != rowlab[r]) ? e : 0.f;
            }
        }
    }

    const int lane = t & 63, wid = t >> 6;
    #pragma unroll
    for (int r = 0; r < TI; ++r) {
        float v = acc[r];
        #pragma unroll
        for (int off = 32; off >= 1; off >>= 1) v += __shfl_down(v, off, 64);
        if (lane == 0) s_part[wid][r] = v;
    }
    __syncthreads();
    if (t < TI) {
        const float tot = s_part[0][t] + s_part[1][t] + s_part[2][t] + s_part[3][t];
        base_row[i0 + t] = MAXL + logf(tot);
    }
}

// ---------------- pass 2: sum over same-label pairs of softplus(base_i - S_ij)/cnt
__global__ __launch_bounds__(256) void pass2_kernel(const float* __restrict__ E,
                                                    const float* __restrict__ base_row,
                                                    const int* __restrict__ cls_cnt,
                                                    const int* __restrict__ cls_off,
                                                    const int* __restrict__ members,
                                                    double* __restrict__ accum) {
    const int c  = blockIdx.x;
    const int mc = cls_cnt[c];
    double local = 0.0;
    if (mc >= 2) {
        const int off = cls_off[c];
        const float inv_cnt = 1.0f / (float)(mc - 1);
        const int npairs = mc * mc;
        for (int p = threadIdx.x; p < npairs; p += blockDim.x) {
            const int a = p / mc, b = p - a * mc;
            if (a == b) continue;
            const int i = members[off + a];
            const int j = members[off + b];
            const float* ei = E + (size_t)i * ND;
            const float* ej = E + (size_t)j * ND;
            float dot = 0.f;
            for (int d = 0; d < ND; d += 4) {
                const float4 x = *(const float4*)(ei + d);
                const float4 y = *(const float4*)(ej + d);
                dot = fmaf(x.x, y.x, dot); dot = fmaf(x.y, y.y, dot);
                dot = fmaf(x.z, y.z, dot); dot = fmaf(x.w, y.w, dot);
            }
            const float xv = base_row[i] - dot * INV_T;
            // stable softplus: log1p(exp(xv))
            const float sp = fmaxf(xv, 0.f) + log1pf(__expf(-fabsf(xv)));
            local += (double)(sp * inv_cnt);
        }
    }
    __shared__ double s_d[4];
    const int lane = threadIdx.x & 63, wid = threadIdx.x >> 6;
    #pragma unroll
    for (int off2 = 32; off2 >= 1; off2 >>= 1)
        local += __shfl_down(local, off2, 64);
    if (lane == 0) s_d[wid] = local;
    __syncthreads();
    if (threadIdx.x == 0) {
        atomicAdd(accum, s_d[0] + s_d[1] + s_d[2] + s_d[3]);
    }
}

__global__ void finalize_kernel(const double* __restrict__ accum, float* __restrict__ out) {
    if (threadIdx.x == 0 && blockIdx.x == 0)
        out[0] = (float)(accum[0] / (double)NB);
}

extern "C" void kernel_launch(void* const* d_in, const int* in_sizes, int n_in,
                              void* d_out, int out_size, void* d_ws, size_t ws_size,
                              hipStream_t stream) {
    const float* E      = (const float*)d_in[0];
    const int*   labels = (const int*)d_in[1];
    float* out = (float*)d_out;

    char* ws = (char*)d_ws;
    double* accum   = (double*)ws;                       // 8 B (16 for alignment slack)
    float*  base_row = (float*)(ws + 16);                // NB*4 = 32 KiB
    int*    cls_cnt = (int*)(ws + 16 + NB * 4);          // 128 ints
    int*    cls_off = cls_cnt + 128;
    int*    cls_cur = cls_off + 128;
    int*    members = cls_cur + 128;                     // NB ints

    hipLaunchKernelGGL(setup_kernel, dim3(1), dim3(256), 0, stream,
                       labels, cls_cnt, cls_off, cls_cur, members, accum);
    hipLaunchKernelGGL(pass1_kernel, dim3(NB / TI), dim3(THREADS), 0, stream,
                       E, labels, base_row);
    hipLaunchKernelGGL(pass2_kernel, dim3(NCLS), dim3(256), 0, stream,
                       E, base_row, cls_cnt, cls_off, members, accum);
    hipLaunchKernelGGL(finalize_kernel, dim3(1), dim3(64), 0, stream, accum, out);
}

// Round 8
// 370.801 us; speedup vs baseline: 7.4043x; 7.4043x over previous
//
#include <hip/hip_runtime.h>
#include <hip/hip_bf16.h>
#include <math.h>

#define NB 8192
#define ND 512
#define NCLS 100

constexpr float INV_T = 1.0f / 0.07f;   // 14.2857143
constexpr float MAXL  = 1.0f / 0.07f;   // fixed LSE max: |dot|<=1 since rows normalized

typedef __attribute__((ext_vector_type(8))) short short8v;
typedef __attribute__((ext_vector_type(4))) float f32x4;

__device__ __forceinline__ ushort f2bf(float x) {
    uint32_t u = __float_as_uint(x);
    uint32_t r = (u + 0x7FFFu + ((u >> 16) & 1u)) >> 16;
    return (ushort)r;
}
__device__ __forceinline__ float bf2f(short v) {
    return __uint_as_float(((uint32_t)(ushort)v) << 16);
}

// ---------------- setup: class histogram + member lists + zero accum --------
__global__ __launch_bounds__(256) void setup_kernel(const int* __restrict__ labels,
                                                    int* cls_cnt, int* cls_off,
                                                    int* cls_cur, int* members,
                                                    double* accum) {
    __shared__ int s_cnt[NCLS];
    const int t = threadIdx.x;
    if (t < NCLS) s_cnt[t] = 0;
    if (t == 0) *accum = 0.0;
    __syncthreads();
    for (int j = t; j < NB; j += blockDim.x) atomicAdd(&s_cnt[labels[j]], 1);
    __syncthreads();
    if (t < NCLS) cls_cnt[t] = s_cnt[t];
    __syncthreads();
    if (t == 0) {
        int off = 0;
        for (int c = 0; c < NCLS; ++c) { cls_off[c] = off; cls_cur[c] = off; off += s_cnt[c]; }
    }
    __syncthreads();
    for (int j = t; j < NB; j += blockDim.x) {
        const int c = labels[j];
        const int pos = atomicAdd(&cls_cur[c], 1);
        members[pos] = j;
    }
}

// ---------------- convert: E f32 -> bf16, zero rowsum ----------------------
__global__ __launch_bounds__(256) void convert_kernel(const float* __restrict__ E,
                                                      ushort* __restrict__ Ebf,
                                                      float* __restrict__ rowsum) {
    const int idx = blockIdx.x * 256 + threadIdx.x;   // grid 4096*256 = NB*ND/4
    const float4 v = ((const float4*)E)[idx];
    ushort4 o;
    o.x = f2bf(v.x); o.y = f2bf(v.y); o.z = f2bf(v.z); o.w = f2bf(v.w);
    ((ushort4*)Ebf)[idx] = o;
    if (idx < NB) rowsum[idx] = 0.f;
}

// ---------------- pass1 MFMA: rowsum[i] += sum_{j in block, lab_j!=lab_i} exp(S_ij - MAXL)
// 128x128 tile per block, K=512 in 8 steps of 64. Swizzled LDS (slot ^= row&7),
// staged with global_load_lds width 16 (pre-swizzled global source).
__global__ __launch_bounds__(256) void pass1_mfma_kernel(const ushort* __restrict__ Ebf,
                                                         const int* __restrict__ labels,
                                                         float* __restrict__ rowsum) {
    __shared__ ushort Atile[128 * 64];
    __shared__ ushort Btile[128 * 64];
    __shared__ float  s_rowsum[128];
    __shared__ int    s_labi[128];
    __shared__ int    s_labj[128];

    const int t    = threadIdx.x;
    const int lane = t & 63;
    const int w    = t >> 6;
    const int wr   = (w >> 1) * 64;      // wave row offset in tile
    const int wc   = (w & 1) * 64;       // wave col offset in tile
    const int cl   = lane & 15;
    const int rg   = lane >> 4;

    const int j0 = blockIdx.x * 128;
    const int i0 = blockIdx.y * 128;

    if (t < 128) { s_rowsum[t] = 0.f; s_labi[t] = labels[i0 + t]; }
    else         { s_labj[t - 128] = labels[j0 + t - 128]; }

    f32x4 acc[4][4];
    #pragma unroll
    for (int m = 0; m < 4; ++m)
        #pragma unroll
        for (int n = 0; n < 4; ++n)
            acc[m][n] = (f32x4){0.f, 0.f, 0.f, 0.f};

    for (int ks = 0; ks < ND / 64; ++ks) {
        if (ks) __syncthreads();   // prev compute done before overwrite
        // stage A and B tiles: each wave issues 4x 1KB per tile
        {
            const ushort* asrc = Ebf + (size_t)i0 * ND + ks * 64;
            const ushort* bsrc = Ebf + (size_t)j0 * ND + ks * 64;
            #pragma unroll
            for (int q = 0; q < 4; ++q) {
                const int o    = (w * 4 + q) * 1024 + lane * 16;  // dest byte in tile
                const int row  = o >> 7;
                const int slot = (o & 127) >> 4;
                const int sl2  = slot ^ (row & 7);
                __builtin_amdgcn_global_load_lds(
                    (const __attribute__((address_space(1))) unsigned int*)(asrc + row * ND + sl2 * 8),
                    (__attribute__((address_space(3))) unsigned int*)((char*)Atile + (w * 4 + q) * 1024),
                    16, 0, 0);
                __builtin_amdgcn_global_load_lds(
                    (const __attribute__((address_space(1))) unsigned int*)(bsrc + row * ND + sl2 * 8),
                    (__attribute__((address_space(3))) unsigned int*)((char*)Btile + (w * 4 + q) * 1024),
                    16, 0, 0);
            }
        }
        __syncthreads();           // drains vmcnt, tiles ready

        #pragma unroll
        for (int kk = 0; kk < 2; ++kk) {
            short8v a[4], b[4];
            #pragma unroll
            for (int m = 0; m < 4; ++m) {
                const int row = wr + m * 16 + cl;
                const int sl  = (kk * 4 + rg) ^ (row & 7);
                a[m] = *(const short8v*)(Atile + row * 64 + sl * 8);
            }
            #pragma unroll
            for (int n = 0; n < 4; ++n) {
                const int row = wc + n * 16 + cl;
                const int sl  = (kk * 4 + rg) ^ (row & 7);
                b[n] = *(const short8v*)(Btile + row * 64 + sl * 8);
            }
            #pragma unroll
            for (int m = 0; m < 4; ++m)
                #pragma unroll
                for (int n = 0; n < 4; ++n)
                    acc[m][n] = __builtin_amdgcn_mfma_f32_16x16x32_bf16(a[m], b[n], acc[m][n], 0, 0, 0);
        }
    }

    // epilogue: masked exp-sum per row
    int ljn[4];
    #pragma unroll
    for (int n = 0; n < 4; ++n) ljn[n] = s_labj[wc + n * 16 + cl];

    #pragma unroll
    for (int m = 0; m < 4; ++m) {
        #pragma unroll
        for (int reg = 0; reg < 4; ++reg) {
            const int rloc = wr + m * 16 + rg * 4 + reg;
            const int li   = s_labi[rloc];
            float s = 0.f;
            #pragma unroll
            for (int n = 0; n < 4; ++n) {
                const float d = acc[m][n][reg];
                const float e = __expf(fmaf(d, INV_T, -MAXL));
                s += (ljn[n] != li) ? e : 0.f;
            }
            s += __shfl_xor(s, 1, 64);
            s += __shfl_xor(s, 2, 64);
            s += __shfl_xor(s, 4, 64);
            s += __shfl_xor(s, 8, 64);
            if (cl == 0) atomicAdd(&s_rowsum[rloc], s);
        }
    }
    __syncthreads();
    if (t < 128) atomicAdd(&rowsum[i0 + t], s_rowsum[t]);
}

// ---------------- pass2: same-label pairs, class-tiled --------------------
// grid (NCLS, 4). Each block: class c, a-chunks of 32 rows staged in LDS (bf16,
// XOR-swizzled), 8 threads per row x 64-dim slices, loop over all members b.
__global__ __launch_bounds__(256) void pass2_kernel(const ushort* __restrict__ Ebf,
                                                    const float* __restrict__ rowsum,
                                                    const int* __restrict__ cls_cnt,
                                                    const int* __restrict__ cls_off,
                                                    const int* __restrict__ members,
                                                    double* __restrict__ accum) {
    __shared__ ushort abuf[32 * 512];
    __shared__ float  s_base[32];
    __shared__ int    s_idx[32];
    __shared__ double sd[4];

    const int c  = blockIdx.x;
    const int mc = cls_cnt[c];
    const int t  = threadIdx.x;
    double dlocal = 0.0;

    if (mc >= 2) {
        const int off = cls_off[c];
        const float inv_cnt = 1.0f / (float)(mc - 1);
        const int r = t >> 3, s = t & 7;

        for (int a0 = blockIdx.y * 32; a0 < mc; a0 += 4 * 32) {
            const int rows = min(32, mc - a0);
            if (t < 32) {
                if (t < rows) {
                    const int i = members[off + a0 + t];
                    s_idx[t]  = i;
                    s_base[t] = MAXL + logf(rowsum[i]);
                } else { s_idx[t] = 0; s_base[t] = 0.f; }
            }
            __syncthreads();
            for (int u = t; u < rows * 64; u += 256) {
                const int rr = u >> 6, sl = u & 63;
                const int sl2 = sl ^ (rr & 7);
                *(short8v*)(abuf + rr * 512 + sl2 * 8) =
                    *(const short8v*)(Ebf + (size_t)s_idx[rr] * ND + sl * 8);
            }
            __syncthreads();

            float fsum = 0.f;
            if (r < rows) {
                const int   i_glob = s_idx[r];
                const float base   = s_base[r];
                for (int b = 0; b < mc; ++b) {
                    const int j = members[off + b];
                    const ushort* ej = Ebf + (size_t)j * ND + s * 64;
                    float d = 0.f;
                    #pragma unroll
                    for (int it = 0; it < 8; ++it) {
                        const short8v ev = *(const short8v*)(ej + it * 8);
                        const int phys = (s * 8 + it) ^ (r & 7);
                        const short8v av = *(const short8v*)(abuf + r * 512 + phys * 8);
                        #pragma unroll
                        for (int e = 0; e < 8; ++e)
                            d = fmaf(bf2f(av[e]), bf2f(ev[e]), d);
                    }
                    d += __shfl_xor(d, 1, 64);
                    d += __shfl_xor(d, 2, 64);
                    d += __shfl_xor(d, 4, 64);
                    if (s == 0 && j != i_glob) {
                        const float xv = base - d * INV_T;
                        const float sp = fmaxf(xv, 0.f) + log1pf(__expf(-fabsf(xv)));
                        fsum += sp;
                    }
                }
            }
            dlocal += (double)(fsum * inv_cnt);
            __syncthreads();   // before abuf overwrite next chunk
        }
    }

    #pragma unroll
    for (int o2 = 32; o2 >= 1; o2 >>= 1) dlocal += __shfl_xor(dlocal, o2, 64);
    const int lane = t & 63, w = t >> 6;
    if (lane == 0) sd[w] = dlocal;
    __syncthreads();
    if (t == 0) atomicAdd(accum, sd[0] + sd[1] + sd[2] + sd[3]);
}

__global__ void finalize_kernel(const double* __restrict__ accum, float* __restrict__ out) {
    if (threadIdx.x == 0 && blockIdx.x == 0)
        out[0] = (float)(accum[0] / (double)NB);
}

// ================= fallback f32 path (proven round-2 kernels) ==============
#define TI 16
#define TJ 4
#define THREADS 256

__global__ __launch_bounds__(THREADS) void pass1_f32_kernel(const float* __restrict__ E,
                                                            const int* __restrict__ labels,
                                                            float* __restrict__ base_row) {
    __shared__ float e_tile[TI][ND];
    __shared__ int   s_rowlab[TI];
    __shared__ float s_part[4][TI];

    const int t  = threadIdx.x;
    const int i0 = blockIdx.x * TI;

    {
        const float4* src = (const float4*)(E + (size_t)i0 * ND);
        float4* dst = (float4*)(&e_tile[0][0]);
        #pragma unroll
        for (int k = 0; k < (TI * ND / 4) / THREADS; ++k)
            dst[t + k * THREADS] = src[t + k * THREADS];
    }
    if (t < TI) s_rowlab[t] = labels[i0 + t];
    __syncthreads();

    int rowlab[TI];
    #pragma unroll
    for (int r = 0; r < TI; ++r) rowlab[r] = s_rowlab[r];
    float acc[TI];
    #pragma unroll
    for (int r = 0; r < TI; ++r) acc[r] = 0.f;

    for (int jt = 0; jt < NB; jt += THREADS * TJ) {
        float dot[TI][TJ];
        #pragma unroll
        for (int r = 0; r < TI; ++r)
            #pragma unroll
            for (int q = 0; q < TJ; ++q) dot[r][q] = 0.f;
        const float* jp[TJ];
        #pragma unroll
        for (int q = 0; q < TJ; ++q) jp[q] = E + (size_t)(jt + t + q * THREADS) * ND;
        for (int d = 0; d < ND; d += 4) {
            float4 ev[TJ];
            #pragma unroll
            for (int q = 0; q < TJ; ++q) ev[q] = *(const float4*)(jp[q] + d);
            #pragma unroll
            for (int r = 0; r < TI; ++r) {
                const float4 er = *(const float4*)(&e_tile[r][d]);
                #pragma unroll
                for (int q = 0; q < TJ; ++q) {
                    dot[r][q] = fmaf(er.x, ev[q].x, dot[r][q]);
                    dot[r][q] = fmaf(er.y, ev[q].y, dot[r][q]);
                    dot[r][q] = fmaf(er.z, ev[q].z, dot[r][q]);
                    dot[r][q] = fmaf(er.w, ev[q].w, dot[r][q]);
                }
            }
        }
        #pragma unroll
        for (int q = 0; q < TJ; ++q) {
            const int lj = labels[jt + t + q * THREADS];
            #pragma unroll
            for (int r = 0; r < TI; ++r) {
                const float e = __expf(dot[r][q] * INV_T - MAXL);
                acc[r] += (lj != rowlab[r]) ? e : 0.f;
            }
        }
    }
    const int lane = t & 63, wid = t >> 6;
    #pragma unroll
    for (int r = 0; r < TI; ++r) {
        float v = acc[r];
        #pragma unroll
        for (int off = 32; off >= 1; off >>= 1) v += __shfl_down(v, off, 64);
        if (lane == 0) s_part[wid][r] = v;
    }
    __syncthreads();
    if (t < TI) {
        const float tot = s_part[0][t] + s_part[1][t] + s_part[2][t] + s_part[3][t];
        base_row[i0 + t] = MAXL + logf(tot);
    }
}

__global__ __launch_bounds__(256) void pass2_f32_kernel(const float* __restrict__ E,
                                                        const float* __restrict__ base_row,
                                                        const int* __restrict__ cls_cnt,
                                                        const int* __restrict__ cls_off,
                                                        const int* __restrict__ members,
                                                        double* __restrict__ accum) {
    const int c  = blockIdx.x;
    const int mc = cls_cnt[c];
    double local = 0.0;
    if (mc >= 2) {
        const int off = cls_off[c];
        const float inv_cnt = 1.0f / (float)(mc - 1);
        const int npairs = mc * mc;
        for (int p = threadIdx.x; p < npairs; p += blockDim.x) {
            const int a = p / mc, b = p - a * mc;
            if (a == b) continue;
            const int i = members[off + a];
            const int j = members[off + b];
            const float* ei = E + (size_t)i * ND;
            const float* ej = E + (size_t)j * ND;
            float dot = 0.f;
            for (int d = 0; d < ND; d += 4) {
                const float4 x = *(const float4*)(ei + d);
                const float4 y = *(const float4*)(ej + d);
                dot = fmaf(x.x, y.x, dot); dot = fmaf(x.y, y.y, dot);
                dot = fmaf(x.z, y.z, dot); dot = fmaf(x.w, y.w, dot);
            }
            const float xv = base_row[i] - dot * INV_T;
            const float sp = fmaxf(xv, 0.f) + log1pf(__expf(-fabsf(xv)));
            local += (double)(sp * inv_cnt);
        }
    }
    __shared__ double s_d[4];
    const int lane = threadIdx.x & 63, wid = threadIdx.x >> 6;
    #pragma unroll
    for (int off2 = 32; off2 >= 1; off2 >>= 1) local += __shfl_down(local, off2, 64);
    if (lane == 0) s_d[wid] = local;
    __syncthreads();
    if (threadIdx.x == 0) atomicAdd(accum, s_d[0] + s_d[1] + s_d[2] + s_d[3]);
}

// ===========================================================================
extern "C" void kernel_launch(void* const* d_in, const int* in_sizes, int n_in,
                              void* d_out, int out_size, void* d_ws, size_t ws_size,
                              hipStream_t stream) {
    const float* E      = (const float*)d_in[0];
    const int*   labels = (const int*)d_in[1];
    float* out = (float*)d_out;

    char* ws = (char*)d_ws;
    double* accum   = (double*)ws;                        // [0,16)
    float*  rowsum  = (float*)(ws + 16);                  // NB f32 (also base_row in fallback)
    int*    cls_cnt = (int*)(ws + 16 + NB * 4);           // 128 ints
    int*    cls_off = cls_cnt + 128;
    int*    cls_cur = cls_off + 128;
    int*    members = cls_cur + 128;                      // NB ints
    size_t  ebf_off = ((16 + (size_t)NB * 4 + 512 * 3 + (size_t)NB * 4) + 63) & ~(size_t)63;
    ushort* Ebf     = (ushort*)(ws + ebf_off);            // NB*ND bf16 = 8 MiB
    const size_t needed = ebf_off + (size_t)NB * ND * 2;

    hipLaunchKernelGGL(setup_kernel, dim3(1), dim3(256), 0, stream,
                       labels, cls_cnt, cls_off, cls_cur, members, accum);

    if (ws_size >= needed) {
        hipLaunchKernelGGL(convert_kernel, dim3(NB * ND / 4 / 256), dim3(256), 0, stream,
                           E, Ebf, rowsum);
        hipLaunchKernelGGL(pass1_mfma_kernel, dim3(NB / 128, NB / 128), dim3(256), 0, stream,
                           Ebf, labels, rowsum);
        hipLaunchKernelGGL(pass2_kernel, dim3(NCLS, 4), dim3(256), 0, stream,
                           Ebf, rowsum, cls_cnt, cls_off, members, accum);
    } else {
        hipLaunchKernelGGL(pass1_f32_kernel, dim3(NB / TI), dim3(THREADS), 0, stream,
                           E, labels, rowsum);
        hipLaunchKernelGGL(pass2_f32_kernel, dim3(NCLS), dim3(256), 0, stream,
                           E, rowsum, cls_cnt, cls_off, members, accum);
    }
    hipLaunchKernelGGL(finalize_kernel, dim3(1), dim3(64), 0, stream, accum, out);
}

// Round 11
// 319.282 us; speedup vs baseline: 8.5991x; 1.1614x over previous
//
#include <hip/hip_runtime.h>
#include <hip/hip_bf16.h>
#include <math.h>

#define NB 8192
#define ND 512
#define NCLS 100

constexpr float INV_T = 1.0f / 0.07f;   // 14.2857143
constexpr float MAXL  = 1.0f / 0.07f;   // fixed LSE max: |dot|<=1 since rows normalized

typedef __attribute__((ext_vector_type(8))) short short8v;
typedef __attribute__((ext_vector_type(4))) float f32x4;

__device__ __forceinline__ ushort f2bf(float x) {
    uint32_t u = __float_as_uint(x);
    uint32_t r = (u + 0x7FFFu + ((u >> 16) & 1u)) >> 16;
    return (ushort)r;
}
__device__ __forceinline__ float bf2f(short v) {
    return __uint_as_float(((uint32_t)(ushort)v) << 16);
}

// ---------------- setup: class histogram + member lists + pair prefix -------
__global__ __launch_bounds__(256) void setup_kernel(const int* __restrict__ labels,
                                                    int* cls_cnt, int* cls_off,
                                                    int* cls_cur, int* members,
                                                    int* pair_off, double* accum) {
    __shared__ int s_cnt[NCLS];
    const int t = threadIdx.x;
    if (t < NCLS) s_cnt[t] = 0;
    if (t == 0) *accum = 0.0;
    __syncthreads();
    for (int j = t; j < NB; j += blockDim.x) atomicAdd(&s_cnt[labels[j]], 1);
    __syncthreads();
    if (t < NCLS) cls_cnt[t] = s_cnt[t];
    __syncthreads();
    if (t == 0) {
        int off = 0, poff = 0;
        for (int c = 0; c < NCLS; ++c) {
            cls_off[c] = off; cls_cur[c] = off; off += s_cnt[c];
            pair_off[c] = poff; poff += s_cnt[c] * s_cnt[c];
        }
        pair_off[NCLS] = poff;
    }
    __syncthreads();
    for (int j = t; j < NB; j += blockDim.x) {
        const int c = labels[j];
        const int pos = atomicAdd(&cls_cur[c], 1);
        members[pos] = j;
    }
}

// ---------------- convert: E f32 -> bf16, zero rowsum ----------------------
__global__ __launch_bounds__(256) void convert_kernel(const float* __restrict__ E,
                                                      ushort* __restrict__ Ebf,
                                                      float* __restrict__ rowsum) {
    const int idx = blockIdx.x * 256 + threadIdx.x;   // grid 4096*256 = NB*ND/4
    const float4 v = ((const float4*)E)[idx];
    ushort4 o;
    o.x = f2bf(v.x); o.y = f2bf(v.y); o.z = f2bf(v.z); o.w = f2bf(v.w);
    ((ushort4*)Ebf)[idx] = o;
    if (idx < NB) rowsum[idx] = 0.f;
}

// ---------------- pass1 MFMA: rowsum[i] += sum_{j in block, lab_j!=lab_i} exp(S_ij - MAXL)
// (unchanged from round 8 — proven passing; 128x128 tile, swizzled LDS,
//  global_load_lds width 16 with pre-swizzled global source)
__global__ __launch_bounds__(256) void pass1_mfma_kernel(const ushort* __restrict__ Ebf,
                                                         const int* __restrict__ labels,
                                                         float* __restrict__ rowsum) {
    __shared__ ushort Atile[128 * 64];
    __shared__ ushort Btile[128 * 64];
    __shared__ float  s_rowsum[128];
    __shared__ int    s_labi[128];
    __shared__ int    s_labj[128];

    const int t    = threadIdx.x;
    const int lane = t & 63;
    const int w    = t >> 6;
    const int wr   = (w >> 1) * 64;      // wave row offset in tile
    const int wc   = (w & 1) * 64;       // wave col offset in tile
    const int cl   = lane & 15;
    const int rg   = lane >> 4;

    const int j0 = blockIdx.x * 128;
    const int i0 = blockIdx.y * 128;

    if (t < 128) { s_rowsum[t] = 0.f; s_labi[t] = labels[i0 + t]; }
    else         { s_labj[t - 128] = labels[j0 + t - 128]; }

    f32x4 acc[4][4];
    #pragma unroll
    for (int m = 0; m < 4; ++m)
        #pragma unroll
        for (int n = 0; n < 4; ++n)
            acc[m][n] = (f32x4){0.f, 0.f, 0.f, 0.f};

    for (int ks = 0; ks < ND / 64; ++ks) {
        if (ks) __syncthreads();   // prev compute done before overwrite
        {
            const ushort* asrc = Ebf + (size_t)i0 * ND + ks * 64;
            const ushort* bsrc = Ebf + (size_t)j0 * ND + ks * 64;
            #pragma unroll
            for (int q = 0; q < 4; ++q) {
                const int o    = (w * 4 + q) * 1024 + lane * 16;  // dest byte in tile
                const int row  = o >> 7;
                const int slot = (o & 127) >> 4;
                const int sl2  = slot ^ (row & 7);
                __builtin_amdgcn_global_load_lds(
                    (const __attribute__((address_space(1))) unsigned int*)(asrc + row * ND + sl2 * 8),
                    (__attribute__((address_space(3))) unsigned int*)((char*)Atile + (w * 4 + q) * 1024),
                    16, 0, 0);
                __builtin_amdgcn_global_load_lds(
                    (const __attribute__((address_space(1))) unsigned int*)(bsrc + row * ND + sl2 * 8),
                    (__attribute__((address_space(3))) unsigned int*)((char*)Btile + (w * 4 + q) * 1024),
                    16, 0, 0);
            }
        }
        __syncthreads();           // drains vmcnt, tiles ready

        #pragma unroll
        for (int kk = 0; kk < 2; ++kk) {
            short8v a[4], b[4];
            #pragma unroll
            for (int m = 0; m < 4; ++m) {
                const int row = wr + m * 16 + cl;
                const int sl  = (kk * 4 + rg) ^ (row & 7);
                a[m] = *(const short8v*)(Atile + row * 64 + sl * 8);
            }
            #pragma unroll
            for (int n = 0; n < 4; ++n) {
                const int row = wc + n * 16 + cl;
                const int sl  = (kk * 4 + rg) ^ (row & 7);
                b[n] = *(const short8v*)(Btile + row * 64 + sl * 8);
            }
            #pragma unroll
            for (int m = 0; m < 4; ++m)
                #pragma unroll
                for (int n = 0; n < 4; ++n)
                    acc[m][n] = __builtin_amdgcn_mfma_f32_16x16x32_bf16(a[m], b[n], acc[m][n], 0, 0, 0);
        }
    }

    // epilogue: masked exp-sum per row
    int ljn[4];
    #pragma unroll
    for (int n = 0; n < 4; ++n) ljn[n] = s_labj[wc + n * 16 + cl];

    #pragma unroll
    for (int m = 0; m < 4; ++m) {
        #pragma unroll
        for (int reg = 0; reg < 4; ++reg) {
            const int rloc = wr + m * 16 + rg * 4 + reg;
            const int li   = s_labi[rloc];
            float s = 0.f;
            #pragma unroll
            for (int n = 0; n < 4; ++n) {
                const float d = acc[m][n][reg];
                const float e = __expf(fmaf(d, INV_T, -MAXL));
                s += (ljn[n] != li) ? e : 0.f;
            }
            s += __shfl_xor(s, 1, 64);
            s += __shfl_xor(s, 2, 64);
            s += __shfl_xor(s, 4, 64);
            s += __shfl_xor(s, 8, 64);
            if (cl == 0) atomicAdd(&s_rowsum[rloc], s);
        }
    }
    __syncthreads();
    if (t < 128) atomicAdd(&rowsum[i0 + t], s_rowsum[t]);
}

// ---------------- pass2: ONE PAIR PER THREAD, grid-stride ------------------
// p in [0, P) with P = sum_c mc^2; binary-search class in LDS prefix, decode
// (a,b), skip diagonal, 512-dim bf16 dot from L2, softplus, double-reduce.
__global__ __launch_bounds__(256) void pass2_pairs_kernel(const ushort* __restrict__ Ebf,
                                                          const float* __restrict__ rowsum,
                                                          const int* __restrict__ cls_cnt,
                                                          const int* __restrict__ cls_off,
                                                          const int* __restrict__ members,
                                                          const int* __restrict__ pair_off,
                                                          double* __restrict__ accum) {
    __shared__ int    s_off[NCLS + 1];
    __shared__ double sd[4];
    const int t = threadIdx.x;
    for (int k = t; k <= NCLS; k += 256) s_off[k] = pair_off[k];
    __syncthreads();
    const int P = s_off[NCLS];

    double dlocal = 0.0;
    for (int p = blockIdx.x * 256 + t; p < P; p += gridDim.x * 256) {
        // largest c with s_off[c] <= p (empty classes can never win the search)
        int lo = 0, hi = NCLS - 1;
        while (lo < hi) {
            const int mid = (lo + hi + 1) >> 1;
            if (s_off[mid] <= p) lo = mid; else hi = mid - 1;
        }
        const int c  = lo;
        const int mc = cls_cnt[c];
        const int q  = p - s_off[c];
        const int a  = q / mc;
        const int b  = q - a * mc;
        if (a == b) continue;
        const int i = members[cls_off[c] + a];
        const int j = members[cls_off[c] + b];

        const ushort* ei = Ebf + (size_t)i * ND;
        const ushort* ej = Ebf + (size_t)j * ND;
        float d = 0.f;
        #pragma unroll 8
        for (int u = 0; u < 64; ++u) {
            const short8v x = *(const short8v*)(ei + u * 8);
            const short8v y = *(const short8v*)(ej + u * 8);
            #pragma unroll
            for (int e = 0; e < 8; ++e)
                d = fmaf(bf2f(x[e]), bf2f(y[e]), d);
        }
        const float base = MAXL + logf(rowsum[i]);
        const float xv   = base - d * INV_T;
        const float sp   = fmaxf(xv, 0.f) + log1pf(__expf(-fabsf(xv)));
        dlocal += (double)(sp / (float)(mc - 1));
    }

    #pragma unroll
    for (int o2 = 32; o2 >= 1; o2 >>= 1) dlocal += __shfl_xor(dlocal, o2, 64);
    const int lane = t & 63, w = t >> 6;
    if (lane == 0) sd[w] = dlocal;
    __syncthreads();
    if (t == 0) {
        const double tot = sd[0] + sd[1] + sd[2] + sd[3];
        if (tot != 0.0) atomicAdd(accum, tot);
    }
}

__global__ void finalize_kernel(const double* __restrict__ accum, float* __restrict__ out) {
    if (threadIdx.x == 0 && blockIdx.x == 0)
        out[0] = (float)(accum[0] / (double)NB);
}

// ================= fallback f32 path (proven round-2 kernels) ==============
#define TI 16
#define TJ 4
#define THREADS 256

__global__ __launch_bounds__(THREADS) void pass1_f32_kernel(const float* __restrict__ E,
                                                            const int* __restrict__ labels,
                                                            float* __restrict__ base_row) {
    __shared__ float e_tile[TI][ND];
    __shared__ int   s_rowlab[TI];
    __shared__ float s_part[4][TI];

    const int t  = threadIdx.x;
    const int i0 = blockIdx.x * TI;

    {
        const float4* src = (const float4*)(E + (size_t)i0 * ND);
        float4* dst = (float4*)(&e_tile[0][0]);
        #pragma unroll
        for (int k = 0; k < (TI * ND / 4) / THREADS; ++k)
            dst[t + k * THREADS] = src[t + k * THREADS];
    }
    if (t < TI) s_rowlab[t] = labels[i0 + t];
    __syncthreads();

    int rowlab[TI];
    #pragma unroll
    for (int r = 0; r < TI; ++r) rowlab[r] = s_rowlab[r];
    float acc[TI];
    #pragma unroll
    for (int r = 0; r < TI; ++r) acc[r] = 0.f;

    for (int jt = 0; jt < NB; jt += THREADS * TJ) {
        float dot[TI][TJ];
        #pragma unroll
        for (int r = 0; r < TI; ++r)
            #pragma unroll
            for (int q = 0; q < TJ; ++q) dot[r][q] = 0.f;
        const float* jp[TJ];
        #pragma unroll
        for (int q = 0; q < TJ; ++q) jp[q] = E + (size_t)(jt + t + q * THREADS) * ND;
        for (int d = 0; d < ND; d += 4) {
            float4 ev[TJ];
            #pragma unroll
            for (int q = 0; q < TJ; ++q) ev[q] = *(const float4*)(jp[q] + d);
            #pragma unroll
            for (int r = 0; r < TI; ++r) {
                const float4 er = *(const float4*)(&e_tile[r][d]);
                #pragma unroll
                for (int q = 0; q < TJ; ++q) {
                    dot[r][q] = fmaf(er.x, ev[q].x, dot[r][q]);
                    dot[r][q] = fmaf(er.y, ev[q].y, dot[r][q]);
                    dot[r][q] = fmaf(er.z, ev[q].z, dot[r][q]);
                    dot[r][q] = fmaf(er.w, ev[q].w, dot[r][q]);
                }
            }
        }
        #pragma unroll
        for (int q = 0; q < TJ; ++q) {
            const int lj = labels[jt + t + q * THREADS];
            #pragma unroll
            for (int r = 0; r < TI; ++r) {
                const float e = __expf(dot[r][q] * INV_T - MAXL);
                acc[r] += (lj != rowlab[r]) ? e : 0.f;
            }
        }
    }
    const int lane = t & 63, wid = t >> 6;
    #pragma unroll
    for (int r = 0; r < TI; ++r) {
        float v = acc[r];
        #pragma unroll
        for (int off = 32; off >= 1; off >>= 1) v += __shfl_down(v, off, 64);
        if (lane == 0) s_part[wid][r] = v;
    }
    __syncthreads();
    if (t < TI) {
        const float tot = s_part[0][t] + s_part[1][t] + s_part[2][t] + s_part[3][t];
        base_row[i0 + t] = MAXL + logf(tot);
    }
}

__global__ __launch_bounds__(256) void pass2_f32_kernel(const float* __restrict__ E,
                                                        const float* __restrict__ base_row,
                                                        const int* __restrict__ cls_cnt,
                                                        const int* __restrict__ cls_off,
                                                        const int* __restrict__ members,
                                                        double* __restrict__ accum) {
    const int c  = blockIdx.x;
    const int mc = cls_cnt[c];
    double local = 0.0;
    if (mc >= 2) {
        const int off = cls_off[c];
        const float inv_cnt = 1.0f / (float)(mc - 1);
        const int npairs = mc * mc;
        for (int p = threadIdx.x; p < npairs; p += blockDim.x) {
            const int a = p / mc, b = p - a * mc;
            if (a == b) continue;
            const int i = members[off + a];
            const int j = members[off + b];
            const float* ei = E + (size_t)i * ND;
            const float* ej = E + (size_t)j * ND;
            float dot = 0.f;
            for (int d = 0; d < ND; d += 4) {
                const float4 x = *(const float4*)(ei + d);
                const float4 y = *(const float4*)(ej + d);
                dot = fmaf(x.x, y.x, dot); dot = fmaf(x.y, y.y, dot);
                dot = fmaf(x.z, y.z, dot); dot = fmaf(x.w, y.w, dot);
            }
            const float xv = base_row[i] - dot * INV_T;
            const float sp = fmaxf(xv, 0.f) + log1pf(__expf(-fabsf(xv)));
            local += (double)(sp * inv_cnt);
        }
    }
    __shared__ double s_d[4];
    const int lane = threadIdx.x & 63, wid = threadIdx.x >> 6;
    #pragma unroll
    for (int off2 = 32; off2 >= 1; off2 >>= 1) local += __shfl_down(local, off2, 64);
    if (lane == 0) s_d[wid] = local;
    __syncthreads();
    if (threadIdx.x == 0) atomicAdd(accum, s_d[0] + s_d[1] + s_d[2] + s_d[3]);
}

// ===========================================================================
extern "C" void kernel_launch(void* const* d_in, const int* in_sizes, int n_in,
                              void* d_out, int out_size, void* d_ws, size_t ws_size,
                              hipStream_t stream) {
    const float* E      = (const float*)d_in[0];
    const int*   labels = (const int*)d_in[1];
    float* out = (float*)d_out;

    char* ws = (char*)d_ws;
    double* accum    = (double*)ws;                       // [0,16)
    float*  rowsum   = (float*)(ws + 16);                 // NB f32 (also base_row in fallback)
    int*    cls_cnt  = (int*)(ws + 16 + NB * 4);          // 128 ints
    int*    cls_off  = cls_cnt + 128;
    int*    cls_cur  = cls_off + 128;
    int*    members  = cls_cur + 128;                     // NB ints
    int*    pair_off = members + NB;                      // 128 ints (uses NCLS+1)
    size_t  ebf_off  = ((16 + (size_t)NB * 4 + 512 * 3 + (size_t)NB * 4 + 512) + 63) & ~(size_t)63;
    ushort* Ebf      = (ushort*)(ws + ebf_off);           // NB*ND bf16 = 8 MiB
    const size_t needed = ebf_off + (size_t)NB * ND * 2;

    hipLaunchKernelGGL(setup_kernel, dim3(1), dim3(256), 0, stream,
                       labels, cls_cnt, cls_off, cls_cur, members, pair_off, accum);

    if (ws_size >= needed) {
        hipLaunchKernelGGL(convert_kernel, dim3(NB * ND / 4 / 256), dim3(256), 0, stream,
                           E, Ebf, rowsum);
        hipLaunchKernelGGL(pass1_mfma_kernel, dim3(NB / 128, NB / 128), dim3(256), 0, stream,
                           Ebf, labels, rowsum);
        hipLaunchKernelGGL(pass2_pairs_kernel, dim3(2048), dim3(256), 0, stream,
                           Ebf, rowsum, cls_cnt, cls_off, members, pair_off, accum);
    } else {
        hipLaunchKernelGGL(pass1_f32_kernel, dim3(NB / TI), dim3(THREADS), 0, stream,
                           E, labels, rowsum);
        hipLaunchKernelGGL(pass2_f32_kernel, dim3(NCLS), dim3(256), 0, stream,
                           E, rowsum, cls_cnt, cls_off, members, accum);
    }
    hipLaunchKernelGGL(finalize_kernel, dim3(1), dim3(64), 0, stream, accum, out);
}

// Round 12
// 296.709 us; speedup vs baseline: 9.2533x; 1.0761x over previous
//
#include <hip/hip_runtime.h>
#include <hip/hip_bf16.h>
#include <math.h>

#define NB 8192
#define ND 512
#define NCLS 100

constexpr float INV_T = 1.0f / 0.07f;   // 14.2857143
constexpr float MAXL  = 1.0f / 0.07f;   // fixed LSE max: |dot|<=1 since rows normalized

typedef __attribute__((ext_vector_type(8))) short short8v;
typedef __attribute__((ext_vector_type(4))) float f32x4;

__device__ __forceinline__ ushort f2bf(float x) {
    uint32_t u = __float_as_uint(x);
    uint32_t r = (u + 0x7FFFu + ((u >> 16) & 1u)) >> 16;
    return (ushort)r;
}
__device__ __forceinline__ float bf2f(short v) {
    return __uint_as_float(((uint32_t)(ushort)v) << 16);
}

// ---------------- setup: class histogram + member lists + pair prefix -------
__global__ __launch_bounds__(256) void setup_kernel(const int* __restrict__ labels,
                                                    int* cls_cnt, int* cls_off,
                                                    int* cls_cur, int* members,
                                                    int* pair_off, double* accum) {
    __shared__ int s_cnt[NCLS];
    const int t = threadIdx.x;
    if (t < NCLS) s_cnt[t] = 0;
    if (t == 0) *accum = 0.0;
    __syncthreads();
    for (int j = t; j < NB; j += blockDim.x) atomicAdd(&s_cnt[labels[j]], 1);
    __syncthreads();
    if (t < NCLS) cls_cnt[t] = s_cnt[t];
    __syncthreads();
    if (t == 0) {
        int off = 0, poff = 0;
        for (int c = 0; c < NCLS; ++c) {
            cls_off[c] = off; cls_cur[c] = off; off += s_cnt[c];
            pair_off[c] = poff; poff += s_cnt[c] * s_cnt[c];
        }
        pair_off[NCLS] = poff;
    }
    __syncthreads();
    for (int j = t; j < NB; j += blockDim.x) {
        const int c = labels[j];
        const int pos = atomicAdd(&cls_cur[c], 1);
        members[pos] = j;
    }
}

// ---------------- convert: E f32 -> bf16, zero rowsum ----------------------
__global__ __launch_bounds__(256) void convert_kernel(const float* __restrict__ E,
                                                      ushort* __restrict__ Ebf,
                                                      float* __restrict__ rowsum) {
    const int idx = blockIdx.x * 256 + threadIdx.x;   // grid 4096*256 = NB*ND/4
    const float4 v = ((const float4*)E)[idx];
    ushort4 o;
    o.x = f2bf(v.x); o.y = f2bf(v.y); o.z = f2bf(v.z); o.w = f2bf(v.w);
    ((ushort4*)Ebf)[idx] = o;
    if (idx < NB) rowsum[idx] = 0.f;
}

// ---------------- pass1 MFMA: rowsum[i] += sum_{j in block, lab_j!=lab_i} exp(S_ij - MAXL)
// (unchanged — proven passing; 128x128 tile, swizzled LDS,
//  global_load_lds width 16 with pre-swizzled global source)
__global__ __launch_bounds__(256) void pass1_mfma_kernel(const ushort* __restrict__ Ebf,
                                                         const int* __restrict__ labels,
                                                         float* __restrict__ rowsum) {
    __shared__ ushort Atile[128 * 64];
    __shared__ ushort Btile[128 * 64];
    __shared__ float  s_rowsum[128];
    __shared__ int    s_labi[128];
    __shared__ int    s_labj[128];

    const int t    = threadIdx.x;
    const int lane = t & 63;
    const int w    = t >> 6;
    const int wr   = (w >> 1) * 64;      // wave row offset in tile
    const int wc   = (w & 1) * 64;       // wave col offset in tile
    const int cl   = lane & 15;
    const int rg   = lane >> 4;

    const int j0 = blockIdx.x * 128;
    const int i0 = blockIdx.y * 128;

    if (t < 128) { s_rowsum[t] = 0.f; s_labi[t] = labels[i0 + t]; }
    else         { s_labj[t - 128] = labels[j0 + t - 128]; }

    f32x4 acc[4][4];
    #pragma unroll
    for (int m = 0; m < 4; ++m)
        #pragma unroll
        for (int n = 0; n < 4; ++n)
            acc[m][n] = (f32x4){0.f, 0.f, 0.f, 0.f};

    for (int ks = 0; ks < ND / 64; ++ks) {
        if (ks) __syncthreads();   // prev compute done before overwrite
        {
            const ushort* asrc = Ebf + (size_t)i0 * ND + ks * 64;
            const ushort* bsrc = Ebf + (size_t)j0 * ND + ks * 64;
            #pragma unroll
            for (int q = 0; q < 4; ++q) {
                const int o    = (w * 4 + q) * 1024 + lane * 16;  // dest byte in tile
                const int row  = o >> 7;
                const int slot = (o & 127) >> 4;
                const int sl2  = slot ^ (row & 7);
                __builtin_amdgcn_global_load_lds(
                    (const __attribute__((address_space(1))) unsigned int*)(asrc + row * ND + sl2 * 8),
                    (__attribute__((address_space(3))) unsigned int*)((char*)Atile + (w * 4 + q) * 1024),
                    16, 0, 0);
                __builtin_amdgcn_global_load_lds(
                    (const __attribute__((address_space(1))) unsigned int*)(bsrc + row * ND + sl2 * 8),
                    (__attribute__((address_space(3))) unsigned int*)((char*)Btile + (w * 4 + q) * 1024),
                    16, 0, 0);
            }
        }
        __syncthreads();           // drains vmcnt, tiles ready

        #pragma unroll
        for (int kk = 0; kk < 2; ++kk) {
            short8v a[4], b[4];
            #pragma unroll
            for (int m = 0; m < 4; ++m) {
                const int row = wr + m * 16 + cl;
                const int sl  = (kk * 4 + rg) ^ (row & 7);
                a[m] = *(const short8v*)(Atile + row * 64 + sl * 8);
            }
            #pragma unroll
            for (int n = 0; n < 4; ++n) {
                const int row = wc + n * 16 + cl;
                const int sl  = (kk * 4 + rg) ^ (row & 7);
                b[n] = *(const short8v*)(Btile + row * 64 + sl * 8);
            }
            #pragma unroll
            for (int m = 0; m < 4; ++m)
                #pragma unroll
                for (int n = 0; n < 4; ++n)
                    acc[m][n] = __builtin_amdgcn_mfma_f32_16x16x32_bf16(a[m], b[n], acc[m][n], 0, 0, 0);
        }
    }

    // epilogue: masked exp-sum per row
    int ljn[4];
    #pragma unroll
    for (int n = 0; n < 4; ++n) ljn[n] = s_labj[wc + n * 16 + cl];

    #pragma unroll
    for (int m = 0; m < 4; ++m) {
        #pragma unroll
        for (int reg = 0; reg < 4; ++reg) {
            const int rloc = wr + m * 16 + rg * 4 + reg;
            const int li   = s_labi[rloc];
            float s = 0.f;
            #pragma unroll
            for (int n = 0; n < 4; ++n) {
                const float d = acc[m][n][reg];
                const float e = __expf(fmaf(d, INV_T, -MAXL));
                s += (ljn[n] != li) ? e : 0.f;
            }
            s += __shfl_xor(s, 1, 64);
            s += __shfl_xor(s, 2, 64);
            s += __shfl_xor(s, 4, 64);
            s += __shfl_xor(s, 8, 64);
            if (cl == 0) atomicAdd(&s_rowsum[rloc], s);
        }
    }
    __syncthreads();
    if (t < 128) atomicAdd(&rowsum[i0 + t], s_rowsum[t]);
}

// ---------------- pass2 v2: 8 LANES PER PAIR (coalesced) -------------------
// Group g (8 lanes) handles pair p: lane s covers elements {s*8 + it*64},
// so at fixed it the 8 lanes read 128 B contiguous from each row. Consecutive
// pairs share the i-row (b varies fastest) -> ei stream is L1-resident.
__global__ __launch_bounds__(256) void pass2_pairs_kernel(const ushort* __restrict__ Ebf,
                                                          const float* __restrict__ rowsum,
                                                          const int* __restrict__ cls_cnt,
                                                          const int* __restrict__ cls_off,
                                                          const int* __restrict__ members,
                                                          const int* __restrict__ pair_off,
                                                          double* __restrict__ accum) {
    __shared__ int    s_off[NCLS + 1];
    __shared__ double sd[4];
    const int t = threadIdx.x;
    for (int k = t; k <= NCLS; k += 256) s_off[k] = pair_off[k];
    __syncthreads();
    const int P = s_off[NCLS];

    const int g  = t >> 3;    // group id within block (32 groups)
    const int s  = t & 7;     // lane within group

    double dlocal = 0.0;
    for (int p = blockIdx.x * 32 + g; p < P; p += gridDim.x * 32) {
        // largest c with s_off[c] <= p (empty classes can never win the search)
        int lo = 0, hi = NCLS - 1;
        while (lo < hi) {
            const int mid = (lo + hi + 1) >> 1;
            if (s_off[mid] <= p) lo = mid; else hi = mid - 1;
        }
        const int c  = lo;
        const int mc = cls_cnt[c];
        const int q  = p - s_off[c];
        const int a  = q / mc;
        const int b  = q - a * mc;
        if (a == b) continue;
        const int i = members[cls_off[c] + a];
        const int j = members[cls_off[c] + b];

        const ushort* ei = Ebf + (size_t)i * ND + s * 8;
        const ushort* ej = Ebf + (size_t)j * ND + s * 8;
        float d = 0.f;
        #pragma unroll
        for (int it = 0; it < 8; ++it) {
            const short8v x = *(const short8v*)(ei + it * 64);
            const short8v y = *(const short8v*)(ej + it * 64);
            #pragma unroll
            for (int e = 0; e < 8; ++e)
                d = fmaf(bf2f(x[e]), bf2f(y[e]), d);
        }
        // reduce across the 8-lane group
        d += __shfl_xor(d, 1, 64);
        d += __shfl_xor(d, 2, 64);
        d += __shfl_xor(d, 4, 64);
        if (s == 0) {
            const float base = MAXL + logf(rowsum[i]);
            const float xv   = base - d * INV_T;
            const float sp   = fmaxf(xv, 0.f) + log1pf(__expf(-fabsf(xv)));
            dlocal += (double)(sp / (float)(mc - 1));
        }
    }

    #pragma unroll
    for (int o2 = 32; o2 >= 1; o2 >>= 1) dlocal += __shfl_xor(dlocal, o2, 64);
    const int lane = t & 63, w = t >> 6;
    if (lane == 0) sd[w] = dlocal;
    __syncthreads();
    if (t == 0) {
        const double tot = sd[0] + sd[1] + sd[2] + sd[3];
        if (tot != 0.0) atomicAdd(accum, tot);
    }
}

__global__ void finalize_kernel(const double* __restrict__ accum, float* __restrict__ out) {
    if (threadIdx.x == 0 && blockIdx.x == 0)
        out[0] = (float)(accum[0] / (double)NB);
}

// ================= fallback f32 path (proven round-2 kernels) ==============
#define TI 16
#define TJ 4
#define THREADS 256

__global__ __launch_bounds__(THREADS) void pass1_f32_kernel(const float* __restrict__ E,
                                                            const int* __restrict__ labels,
                                                            float* __restrict__ base_row) {
    __shared__ float e_tile[TI][ND];
    __shared__ int   s_rowlab[TI];
    __shared__ float s_part[4][TI];

    const int t  = threadIdx.x;
    const int i0 = blockIdx.x * TI;

    {
        const float4* src = (const float4*)(E + (size_t)i0 * ND);
        float4* dst = (float4*)(&e_tile[0][0]);
        #pragma unroll
        for (int k = 0; k < (TI * ND / 4) / THREADS; ++k)
            dst[t + k * THREADS] = src[t + k * THREADS];
    }
    if (t < TI) s_rowlab[t] = labels[i0 + t];
    __syncthreads();

    int rowlab[TI];
    #pragma unroll
    for (int r = 0; r < TI; ++r) rowlab[r] = s_rowlab[r];
    float acc[TI];
    #pragma unroll
    for (int r = 0; r < TI; ++r) acc[r] = 0.f;

    for (int jt = 0; jt < NB; jt += THREADS * TJ) {
        float dot[TI][TJ];
        #pragma unroll
        for (int r = 0; r < TI; ++r)
            #pragma unroll
            for (int q = 0; q < TJ; ++q) dot[r][q] = 0.f;
        const float* jp[TJ];
        #pragma unroll
        for (int q = 0; q < TJ; ++q) jp[q] = E + (size_t)(jt + t + q * THREADS) * ND;
        for (int d = 0; d < ND; d += 4) {
            float4 ev[TJ];
            #pragma unroll
            for (int q = 0; q < TJ; ++q) ev[q] = *(const float4*)(jp[q] + d);
            #pragma unroll
            for (int r = 0; r < TI; ++r) {
                const float4 er = *(const float4*)(&e_tile[r][d]);
                #pragma unroll
                for (int q = 0; q < TJ; ++q) {
                    dot[r][q] = fmaf(er.x, ev[q].x, dot[r][q]);
                    dot[r][q] = fmaf(er.y, ev[q].y, dot[r][q]);
                    dot[r][q] = fmaf(er.z, ev[q].z, dot[r][q]);
                    dot[r][q] = fmaf(er.w, ev[q].w, dot[r][q]);
                }
            }
        }
        #pragma unroll
        for (int q = 0; q < TJ; ++q) {
            const int lj = labels[jt + t + q * THREADS];
            #pragma unroll
            for (int r = 0; r < TI; ++r) {
                const float e = __expf(dot[r][q] * INV_T - MAXL);
                acc[r] += (lj != rowlab[r]) ? e : 0.f;
            }
        }
    }
    const int lane = t & 63, wid = t >> 6;
    #pragma unroll
    for (int r = 0; r < TI; ++r) {
        float v = acc[r];
        #pragma unroll
        for (int off = 32; off >= 1; off >>= 1) v += __shfl_down(v, off, 64);
        if (lane == 0) s_part[wid][r] = v;
    }
    __syncthreads();
    if (t < TI) {
        const float tot = s_part[0][t] + s_part[1][t] + s_part[2][t] + s_part[3][t];
        base_row[i0 + t] = MAXL + logf(tot);
    }
}

__global__ __launch_bounds__(256) void pass2_f32_kernel(const float* __restrict__ E,
                                                        const float* __restrict__ base_row,
                                                        const int* __restrict__ cls_cnt,
                                                        const int* __restrict__ cls_off,
                                                        const int* __restrict__ members,
                                                        double* __restrict__ accum) {
    const int c  = blockIdx.x;
    const int mc = cls_cnt[c];
    double local = 0.0;
    if (mc >= 2) {
        const int off = cls_off[c];
        const float inv_cnt = 1.0f / (float)(mc - 1);
        const int npairs = mc * mc;
        for (int p = threadIdx.x; p < npairs; p += blockDim.x) {
            const int a = p / mc, b = p - a * mc;
            if (a == b) continue;
            const int i = members[off + a];
            const int j = members[off + b];
            const float* ei = E + (size_t)i * ND;
            const float* ej = E + (size_t)j * ND;
            float dot = 0.f;
            for (int d = 0; d < ND; d += 4) {
                const float4 x = *(const float4*)(ei + d);
                const float4 y = *(const float4*)(ej + d);
                dot = fmaf(x.x, y.x, dot); dot = fmaf(x.y, y.y, dot);
                dot = fmaf(x.z, y.z, dot); dot = fmaf(x.w, y.w, dot);
            }
            const float xv = base_row[i] - dot * INV_T;
            const float sp = fmaxf(xv, 0.f) + log1pf(__expf(-fabsf(xv)));
            local += (double)(sp * inv_cnt);
        }
    }
    __shared__ double s_d[4];
    const int lane = threadIdx.x & 63, wid = threadIdx.x >> 6;
    #pragma unroll
    for (int off2 = 32; off2 >= 1; off2 >>= 1) local += __shfl_down(local, off2, 64);
    if (lane == 0) s_d[wid] = local;
    __syncthreads();
    if (threadIdx.x == 0) atomicAdd(accum, s_d[0] + s_d[1] + s_d[2] + s_d[3]);
}

// ===========================================================================
extern "C" void kernel_launch(void* const* d_in, const int* in_sizes, int n_in,
                              void* d_out, int out_size, void* d_ws, size_t ws_size,
                              hipStream_t stream) {
    const float* E      = (const float*)d_in[0];
    const int*   labels = (const int*)d_in[1];
    float* out = (float*)d_out;

    char* ws = (char*)d_ws;
    double* accum    = (double*)ws;                       // [0,16)
    float*  rowsum   = (float*)(ws + 16);                 // NB f32 (also base_row in fallback)
    int*    cls_cnt  = (int*)(ws + 16 + NB * 4);          // 128 ints
    int*    cls_off  = cls_cnt + 128;
    int*    cls_cur  = cls_off + 128;
    int*    members  = cls_cur + 128;                     // NB ints
    int*    pair_off = members + NB;                      // 128 ints (uses NCLS+1)
    size_t  ebf_off  = ((16 + (size_t)NB * 4 + 512 * 3 + (size_t)NB * 4 + 512) + 63) & ~(size_t)63;
    ushort* Ebf      = (ushort*)(ws + ebf_off);           // NB*ND bf16 = 8 MiB
    const size_t needed = ebf_off + (size_t)NB * ND * 2;

    hipLaunchKernelGGL(setup_kernel, dim3(1), dim3(256), 0, stream,
                       labels, cls_cnt, cls_off, cls_cur, members, pair_off, accum);

    if (ws_size >= needed) {
        hipLaunchKernelGGL(convert_kernel, dim3(NB * ND / 4 / 256), dim3(256), 0, stream,
                           E, Ebf, rowsum);
        hipLaunchKernelGGL(pass1_mfma_kernel, dim3(NB / 128, NB / 128), dim3(256), 0, stream,
                           Ebf, labels, rowsum);
        hipLaunchKernelGGL(pass2_pairs_kernel, dim3(4096), dim3(256), 0, stream,
                           Ebf, rowsum, cls_cnt, cls_off, members, pair_off, accum);
    } else {
        hipLaunchKernelGGL(pass1_f32_kernel, dim3(NB / TI), dim3(THREADS), 0, stream,
                           E, labels, rowsum);
        hipLaunchKernelGGL(pass2_f32_kernel, dim3(NCLS), dim3(256), 0, stream,
                           E, rowsum, cls_cnt, cls_off, members, accum);
    }
    hipLaunchKernelGGL(finalize_kernel, dim3(1), dim3(64), 0, stream, accum, out);
}

// Round 13
// 275.369 us; speedup vs baseline: 9.9704x; 1.0775x over previous
//
#include <hip/hip_runtime.h>
#include <hip/hip_bf16.h>
#include <math.h>

#define NB 8192
#define ND 512
#define NCLS 100

constexpr float INV_T = 1.0f / 0.07f;   // 14.2857143
constexpr float MAXL  = 1.0f / 0.07f;   // fixed LSE max: |dot|<=1 since rows normalized

typedef __attribute__((ext_vector_type(8))) short short8v;
typedef __attribute__((ext_vector_type(4))) float f32x4;

__device__ __forceinline__ ushort f2bf(float x) {
    uint32_t u = __float_as_uint(x);
    uint32_t r = (u + 0x7FFFu + ((u >> 16) & 1u)) >> 16;
    return (ushort)r;
}
__device__ __forceinline__ float bf2f(short v) {
    return __uint_as_float(((uint32_t)(ushort)v) << 16);
}

// ---------------- setup: class histogram + member lists + pair prefix -------
__global__ __launch_bounds__(256) void setup_kernel(const int* __restrict__ labels,
                                                    int* cls_cnt, int* cls_off,
                                                    int* cls_cur, int* members,
                                                    int* pair_off, double* accum) {
    __shared__ int s_cnt[NCLS];
    const int t = threadIdx.x;
    if (t < NCLS) s_cnt[t] = 0;
    if (t == 0) *accum = 0.0;
    __syncthreads();
    for (int j = t; j < NB; j += blockDim.x) atomicAdd(&s_cnt[labels[j]], 1);
    __syncthreads();
    if (t < NCLS) cls_cnt[t] = s_cnt[t];
    __syncthreads();
    if (t == 0) {
        int off = 0, poff = 0;
        for (int c = 0; c < NCLS; ++c) {
            cls_off[c] = off; cls_cur[c] = off; off += s_cnt[c];
            pair_off[c] = poff; poff += s_cnt[c] * s_cnt[c];
        }
        pair_off[NCLS] = poff;
    }
    __syncthreads();
    for (int j = t; j < NB; j += blockDim.x) {
        const int c = labels[j];
        const int pos = atomicAdd(&cls_cur[c], 1);
        members[pos] = j;
    }
}

// ---------------- convert: E f32 -> bf16, zero rowsum ----------------------
__global__ __launch_bounds__(256) void convert_kernel(const float* __restrict__ E,
                                                      ushort* __restrict__ Ebf,
                                                      float* __restrict__ rowsum) {
    const int idx = blockIdx.x * 256 + threadIdx.x;   // grid 4096*256 = NB*ND/4
    const float4 v = ((const float4*)E)[idx];
    ushort4 o;
    o.x = f2bf(v.x); o.y = f2bf(v.y); o.z = f2bf(v.z); o.w = f2bf(v.w);
    ((ushort4*)Ebf)[idx] = o;
    if (idx < NB) rowsum[idx] = 0.f;
}

// ---------------- pass1 MFMA, SYMMETRIC (upper-triangle blocks only) -------
// Block (bi<=bj) computes the 128x128 tile; emits row-sums into rowsum[i-range]
// and (off-diagonal only) col-sums into rowsum[j-range] using S symmetry.
__global__ __launch_bounds__(256) void pass1_mfma_kernel(const ushort* __restrict__ Ebf,
                                                         const int* __restrict__ labels,
                                                         float* __restrict__ rowsum) {
    const int bj = blockIdx.x, bi = blockIdx.y;
    if (bj < bi) return;                 // lower triangle: symmetry-covered

    __shared__ ushort Atile[128 * 64];
    __shared__ ushort Btile[128 * 64];
    __shared__ float  s_rowsum[128];
    __shared__ float  s_colsum[128];
    __shared__ int    s_labi[128];
    __shared__ int    s_labj[128];

    const int t    = threadIdx.x;
    const int lane = t & 63;
    const int w    = t >> 6;
    const int wr   = (w >> 1) * 64;      // wave row offset in tile
    const int wc   = (w & 1) * 64;       // wave col offset in tile
    const int cl   = lane & 15;
    const int rg   = lane >> 4;

    const int j0 = bj * 128;
    const int i0 = bi * 128;

    if (t < 128) { s_rowsum[t] = 0.f; s_colsum[t] = 0.f; s_labi[t] = labels[i0 + t]; }
    else         { s_labj[t - 128] = labels[j0 + t - 128]; }

    f32x4 acc[4][4];
    #pragma unroll
    for (int m = 0; m < 4; ++m)
        #pragma unroll
        for (int n = 0; n < 4; ++n)
            acc[m][n] = (f32x4){0.f, 0.f, 0.f, 0.f};

    for (int ks = 0; ks < ND / 64; ++ks) {
        if (ks) __syncthreads();   // prev compute done before overwrite
        {
            const ushort* asrc = Ebf + (size_t)i0 * ND + ks * 64;
            const ushort* bsrc = Ebf + (size_t)j0 * ND + ks * 64;
            #pragma unroll
            for (int q = 0; q < 4; ++q) {
                const int o    = (w * 4 + q) * 1024 + lane * 16;  // dest byte in tile
                const int row  = o >> 7;
                const int slot = (o & 127) >> 4;
                const int sl2  = slot ^ (row & 7);
                __builtin_amdgcn_global_load_lds(
                    (const __attribute__((address_space(1))) unsigned int*)(asrc + row * ND + sl2 * 8),
                    (__attribute__((address_space(3))) unsigned int*)((char*)Atile + (w * 4 + q) * 1024),
                    16, 0, 0);
                __builtin_amdgcn_global_load_lds(
                    (const __attribute__((address_space(1))) unsigned int*)(bsrc + row * ND + sl2 * 8),
                    (__attribute__((address_space(3))) unsigned int*)((char*)Btile + (w * 4 + q) * 1024),
                    16, 0, 0);
            }
        }
        __syncthreads();           // drains vmcnt, tiles ready

        #pragma unroll
        for (int kk = 0; kk < 2; ++kk) {
            short8v a[4], b[4];
            #pragma unroll
            for (int m = 0; m < 4; ++m) {
                const int row = wr + m * 16 + cl;
                const int sl  = (kk * 4 + rg) ^ (row & 7);
                a[m] = *(const short8v*)(Atile + row * 64 + sl * 8);
            }
            #pragma unroll
            for (int n = 0; n < 4; ++n) {
                const int row = wc + n * 16 + cl;
                const int sl  = (kk * 4 + rg) ^ (row & 7);
                b[n] = *(const short8v*)(Btile + row * 64 + sl * 8);
            }
            #pragma unroll
            for (int m = 0; m < 4; ++m)
                #pragma unroll
                for (int n = 0; n < 4; ++n)
                    acc[m][n] = __builtin_amdgcn_mfma_f32_16x16x32_bf16(a[m], b[n], acc[m][n], 0, 0, 0);
        }
    }

    // epilogue: masked exp; row-sums (reduce over cl) + col-sums (reduce over rg)
    int ljn[4];
    #pragma unroll
    for (int n = 0; n < 4; ++n) ljn[n] = s_labj[wc + n * 16 + cl];

    float cs[4] = {0.f, 0.f, 0.f, 0.f};
    #pragma unroll
    for (int m = 0; m < 4; ++m) {
        #pragma unroll
        for (int reg = 0; reg < 4; ++reg) {
            const int rloc = wr + m * 16 + rg * 4 + reg;
            const int li   = s_labi[rloc];
            float rs = 0.f;
            #pragma unroll
            for (int n = 0; n < 4; ++n) {
                const float d = acc[m][n][reg];
                const float e = __expf(fmaf(d, INV_T, -MAXL));
                const float msk = (ljn[n] != li) ? e : 0.f;
                rs += msk;
                cs[n] += msk;
            }
            rs += __shfl_xor(rs, 1, 64);
            rs += __shfl_xor(rs, 2, 64);
            rs += __shfl_xor(rs, 4, 64);
            rs += __shfl_xor(rs, 8, 64);
            if (cl == 0) atomicAdd(&s_rowsum[rloc], rs);
        }
    }
    #pragma unroll
    for (int n = 0; n < 4; ++n) {
        float c = cs[n];
        c += __shfl_xor(c, 16, 64);
        c += __shfl_xor(c, 32, 64);
        if (rg == 0) atomicAdd(&s_colsum[wc + n * 16 + cl], c);
    }
    __syncthreads();
    if (t < 128) {
        atomicAdd(&rowsum[i0 + t], s_rowsum[t]);
        if (i0 != j0) atomicAdd(&rowsum[j0 + t], s_colsum[t]);
    }
}

// ---------------- pass2 v2: 8 LANES PER PAIR (coalesced) -------------------
__global__ __launch_bounds__(256) void pass2_pairs_kernel(const ushort* __restrict__ Ebf,
                                                          const float* __restrict__ rowsum,
                                                          const int* __restrict__ cls_cnt,
                                                          const int* __restrict__ cls_off,
                                                          const int* __restrict__ members,
                                                          const int* __restrict__ pair_off,
                                                          double* __restrict__ accum) {
    __shared__ int    s_off[NCLS + 1];
    __shared__ double sd[4];
    const int t = threadIdx.x;
    for (int k = t; k <= NCLS; k += 256) s_off[k] = pair_off[k];
    __syncthreads();
    const int P = s_off[NCLS];

    const int g  = t >> 3;    // group id within block (32 groups)
    const int s  = t & 7;     // lane within group

    double dlocal = 0.0;
    for (int p = blockIdx.x * 32 + g; p < P; p += gridDim.x * 32) {
        int lo = 0, hi = NCLS - 1;
        while (lo < hi) {
            const int mid = (lo + hi + 1) >> 1;
            if (s_off[mid] <= p) lo = mid; else hi = mid - 1;
        }
        const int c  = lo;
        const int mc = cls_cnt[c];
        const int q  = p - s_off[c];
        const int a  = q / mc;
        const int b  = q - a * mc;
        if (a == b) continue;
        const int i = members[cls_off[c] + a];
        const int j = members[cls_off[c] + b];

        const ushort* ei = Ebf + (size_t)i * ND + s * 8;
        const ushort* ej = Ebf + (size_t)j * ND + s * 8;
        float d = 0.f;
        #pragma unroll
        for (int it = 0; it < 8; ++it) {
            const short8v x = *(const short8v*)(ei + it * 64);
            const short8v y = *(const short8v*)(ej + it * 64);
            #pragma unroll
            for (int e = 0; e < 8; ++e)
                d = fmaf(bf2f(x[e]), bf2f(y[e]), d);
        }
        d += __shfl_xor(d, 1, 64);
        d += __shfl_xor(d, 2, 64);
        d += __shfl_xor(d, 4, 64);
        if (s == 0) {
            const float base = MAXL + logf(rowsum[i]);
            const float xv   = base - d * INV_T;
            const float sp   = fmaxf(xv, 0.f) + log1pf(__expf(-fabsf(xv)));
            dlocal += (double)(sp / (float)(mc - 1));
        }
    }

    #pragma unroll
    for (int o2 = 32; o2 >= 1; o2 >>= 1) dlocal += __shfl_xor(dlocal, o2, 64);
    const int lane = t & 63, w = t >> 6;
    if (lane == 0) sd[w] = dlocal;
    __syncthreads();
    if (t == 0) {
        const double tot = sd[0] + sd[1] + sd[2] + sd[3];
        if (tot != 0.0) atomicAdd(accum, tot);
    }
}

__global__ void finalize_kernel(const double* __restrict__ accum, float* __restrict__ out) {
    if (threadIdx.x == 0 && blockIdx.x == 0)
        out[0] = (float)(accum[0] / (double)NB);
}

// ================= fallback f32 path (proven round-2 kernels) ==============
#define TI 16
#define TJ 4
#define THREADS 256

__global__ __launch_bounds__(THREADS) void pass1_f32_kernel(const float* __restrict__ E,
                                                            const int* __restrict__ labels,
                                                            float* __restrict__ base_row) {
    __shared__ float e_tile[TI][ND];
    __shared__ int   s_rowlab[TI];
    __shared__ float s_part[4][TI];

    const int t  = threadIdx.x;
    const int i0 = blockIdx.x * TI;

    {
        const float4* src = (const float4*)(E + (size_t)i0 * ND);
        float4* dst = (float4*)(&e_tile[0][0]);
        #pragma unroll
        for (int k = 0; k < (TI * ND / 4) / THREADS; ++k)
            dst[t + k * THREADS] = src[t + k * THREADS];
    }
    if (t < TI) s_rowlab[t] = labels[i0 + t];
    __syncthreads();

    int rowlab[TI];
    #pragma unroll
    for (int r = 0; r < TI; ++r) rowlab[r] = s_rowlab[r];
    float acc[TI];
    #pragma unroll
    for (int r = 0; r < TI; ++r) acc[r] = 0.f;

    for (int jt = 0; jt < NB; jt += THREADS * TJ) {
        float dot[TI][TJ];
        #pragma unroll
        for (int r = 0; r < TI; ++r)
            #pragma unroll
            for (int q = 0; q < TJ; ++q) dot[r][q] = 0.f;
        const float* jp[TJ];
        #pragma unroll
        for (int q = 0; q < TJ; ++q) jp[q] = E + (size_t)(jt + t + q * THREADS) * ND;
        for (int d = 0; d < ND; d += 4) {
            float4 ev[TJ];
            #pragma unroll
            for (int q = 0; q < TJ; ++q) ev[q] = *(const float4*)(jp[q] + d);
            #pragma unroll
            for (int r = 0; r < TI; ++r) {
                const float4 er = *(const float4*)(&e_tile[r][d]);
                #pragma unroll
                for (int q = 0; q < TJ; ++q) {
                    dot[r][q] = fmaf(er.x, ev[q].x, dot[r][q]);
                    dot[r][q] = fmaf(er.y, ev[q].y, dot[r][q]);
                    dot[r][q] = fmaf(er.z, ev[q].z, dot[r][q]);
                    dot[r][q] = fmaf(er.w, ev[q].w, dot[r][q]);
                }
            }
        }
        #pragma unroll
        for (int q = 0; q < TJ; ++q) {
            const int lj = labels[jt + t + q * THREADS];
            #pragma unroll
            for (int r = 0; r < TI; ++r) {
                const float e = __expf(dot[r][q] * INV_T - MAXL);
                acc[r] += (lj != rowlab[r]) ? e : 0.f;
            }
        }
    }
    const int lane = t & 63, wid = t >> 6;
    #pragma unroll
    for (int r = 0; r < TI; ++r) {
        float v = acc[r];
        #pragma unroll
        for (int off = 32; off >= 1; off >>= 1) v += __shfl_down(v, off, 64);
        if (lane == 0) s_part[wid][r] = v;
    }
    __syncthreads();
    if (t < TI) {
        const float tot = s_part[0][t] + s_part[1][t] + s_part[2][t] + s_part[3][t];
        base_row[i0 + t] = MAXL + logf(tot);
    }
}

__global__ __launch_bounds__(256) void pass2_f32_kernel(const float* __restrict__ E,
                                                        const float* __restrict__ base_row,
                                                        const int* __restrict__ cls_cnt,
                                                        const int* __restrict__ cls_off,
                                                        const int* __restrict__ members,
                                                        double* __restrict__ accum) {
    const int c  = blockIdx.x;
    const int mc = cls_cnt[c];
    double local = 0.0;
    if (mc >= 2) {
        const int off = cls_off[c];
        const float inv_cnt = 1.0f / (float)(mc - 1);
        const int npairs = mc * mc;
        for (int p = threadIdx.x; p < npairs; p += blockDim.x) {
            const int a = p / mc, b = p - a * mc;
            if (a == b) continue;
            const int i = members[off + a];
            const int j = members[off + b];
            const float* ei = E + (size_t)i * ND;
            const float* ej = E + (size_t)j * ND;
            float dot = 0.f;
            for (int d = 0; d < ND; d += 4) {
                const float4 x = *(const float4*)(ei + d);
                const float4 y = *(const float4*)(ej + d);
                dot = fmaf(x.x, y.x, dot); dot = fmaf(x.y, y.y, dot);
                dot = fmaf(x.z, y.z, dot); dot = fmaf(x.w, y.w, dot);
            }
            const float xv = base_row[i] - dot * INV_T;
            const float sp = fmaxf(xv, 0.f) + log1pf(__expf(-fabsf(xv)));
            local += (double)(sp * inv_cnt);
        }
    }
    __shared__ double s_d[4];
    const int lane = threadIdx.x & 63, wid = threadIdx.x >> 6;
    #pragma unroll
    for (int off2 = 32; off2 >= 1; off2 >>= 1) local += __shfl_down(local, off2, 64);
    if (lane == 0) s_d[wid] = local;
    __syncthreads();
    if (threadIdx.x == 0) atomicAdd(accum, s_d[0] + s_d[1] + s_d[2] + s_d[3]);
}

// ===========================================================================
extern "C" void kernel_launch(void* const* d_in, const int* in_sizes, int n_in,
                              void* d_out, int out_size, void* d_ws, size_t ws_size,
                              hipStream_t stream) {
    const float* E      = (const float*)d_in[0];
    const int*   labels = (const int*)d_in[1];
    float* out = (float*)d_out;

    char* ws = (char*)d_ws;
    double* accum    = (double*)ws;                       // [0,16)
    float*  rowsum   = (float*)(ws + 16);                 // NB f32 (also base_row in fallback)
    int*    cls_cnt  = (int*)(ws + 16 + NB * 4);          // 128 ints
    int*    cls_off  = cls_cnt + 128;
    int*    cls_cur  = cls_off + 128;
    int*    members  = cls_cur + 128;                     // NB ints
    int*    pair_off = members + NB;                      // 128 ints (uses NCLS+1)
    size_t  ebf_off  = ((16 + (size_t)NB * 4 + 512 * 3 + (size_t)NB * 4 + 512) + 63) & ~(size_t)63;
    ushort* Ebf      = (ushort*)(ws + ebf_off);           // NB*ND bf16 = 8 MiB
    const size_t needed = ebf_off + (size_t)NB * ND * 2;

    hipLaunchKernelGGL(setup_kernel, dim3(1), dim3(256), 0, stream,
                       labels, cls_cnt, cls_off, cls_cur, members, pair_off, accum);

    if (ws_size >= needed) {
        hipLaunchKernelGGL(convert_kernel, dim3(NB * ND / 4 / 256), dim3(256), 0, stream,
                           E, Ebf, rowsum);
        hipLaunchKernelGGL(pass1_mfma_kernel, dim3(NB / 128, NB / 128), dim3(256), 0, stream,
                           Ebf, labels, rowsum);
        hipLaunchKernelGGL(pass2_pairs_kernel, dim3(4096), dim3(256), 0, stream,
                           Ebf, rowsum, cls_cnt, cls_off, members, pair_off, accum);
    } else {
        hipLaunchKernelGGL(pass1_f32_kernel, dim3(NB / TI), dim3(THREADS), 0, stream,
                           E, labels, rowsum);
        hipLaunchKernelGGL(pass2_f32_kernel, dim3(NCLS), dim3(256), 0, stream,
                           E, rowsum, cls_cnt, cls_off, members, accum);
    }
    hipLaunchKernelGGL(finalize_kernel, dim3(1), dim3(64), 0, stream, accum, out);
}